// Round 14
// baseline (194.881 us; speedup 1.0000x reference)
//
#include <hip/hip_runtime.h>
#include <cstdint>

// ---------------------------------------------------------------------------
// RotationScan: theta/retain/inp GEMM -> chunked complex scan -> out GEMM -> LN
// B=4 T=4096 D=1024 SD=512 CHUNK=32
// r14 = r13 + NEW gemm8p for GEMM2: m201-faithful half-tile schedule
// (4 half-slots/operand, A(kt+1)@ph0/ph1 + B(kt+2)@ph2/ph3 staging, single
// vmcnt(4) publish at ph3, per-phase reads issued BEFORE the barrier).
// GEMM1 keeps r13's reg-staged gemm256<true> (timed ~79us, session best).
// ---------------------------------------------------------------------------

typedef __bf16 bf16x8 __attribute__((ext_vector_type(8)));
typedef float  f32x4  __attribute__((ext_vector_type(4)));
typedef ushort u16x8  __attribute__((ext_vector_type(8)));

#define AS1 __attribute__((address_space(1)))
#define AS3 __attribute__((address_space(3)))

__device__ __forceinline__ void gload16(const void* g, void* l) {
  __builtin_amdgcn_global_load_lds((const AS1 void*)g, (AS3 void*)l, 16, 0, 0);
}

__device__ __forceinline__ ushort f2bf(float f) {
  union { float f; uint32_t u; } v; v.f = f;
  uint32_t u = v.u;
  uint32_t r = u + 0x7FFFu + ((u >> 16) & 1u);   // RNE
  return (ushort)(r >> 16);
}
__device__ __forceinline__ float bf2f(ushort u) {
  union { uint32_t x; float f; } v; v.x = (uint32_t)u << 16; return v.f;
}
__device__ __forceinline__ u16x8 cvt8(float4 a, float4 b) {
  u16x8 o;
  o[0] = f2bf(a.x); o[1] = f2bf(a.y); o[2] = f2bf(a.z); o[3] = f2bf(a.w);
  o[4] = f2bf(b.x); o[5] = f2bf(b.y); o[6] = f2bf(b.z); o[7] = f2bf(b.w);
  return o;
}

// ---------------------------------------------------------------------------
// Fused transpose + f32->bf16 for all 4 weights (one launch).
// ---------------------------------------------------------------------------
__global__ __launch_bounds__(256) void tconv_all(const float* __restrict__ Wt,
                                                 const float* __restrict__ Wr,
                                                 const float* __restrict__ Wi,
                                                 const float* __restrict__ Wo,
                                                 ushort* __restrict__ wcat,
                                                 ushort* __restrict__ wot) {
  const int z = blockIdx.z;
  if (z < 2 && blockIdx.x >= 16) return;          // C=512 weights: 16 col-blocks
  const float* src = (z == 0) ? Wt : (z == 1) ? Wr : (z == 2) ? Wi : Wo;
  const int C = (z < 2) ? 512 : 1024;
  const int row_off = (z == 0) ? 0 : (z == 1) ? 512 : (z == 2) ? 1024 : 0;
  ushort* dst = (z == 3) ? wot : wcat;

  __shared__ float tile[32][33];
  int tx = threadIdx.x, ty = threadIdx.y;
  int rb = blockIdx.y * 32, cb = blockIdx.x * 32;
#pragma unroll
  for (int yy = 0; yy < 4; ++yy) {
    int r = rb + ty + yy * 8;
    tile[ty + yy * 8][tx] = src[(size_t)r * C + cb + tx];
  }
  __syncthreads();
#pragma unroll
  for (int yy = 0; yy < 4; ++yy) {
    int c = cb + ty + yy * 8;
    dst[(size_t)(row_off + c) * 1024 + rb + tx] = f2bf(tile[tx][ty + yy * 8]);
  }
}

__global__ __launch_bounds__(256) void pack_bias(const float* __restrict__ bt,
                                                 const float* __restrict__ br,
                                                 const float* __restrict__ bi,
                                                 float* __restrict__ bcat) {
  int i = blockIdx.x * 256 + threadIdx.x;          // 0..2047
  bcat[i] = (i < 512) ? bt[i] : (i < 1024 ? br[i - 512] : bi[i - 1024]);
}

// ---------------------------------------------------------------------------
// r13 gemm256 (GEMM1 path, AF32 reg-staged A with 1-tile-deep prefetch).
// ---------------------------------------------------------------------------
template <bool AF32>
__global__ __launch_bounds__(512, 2) void gemm256(const void* __restrict__ Aptr,
                                                  const ushort* __restrict__ Bt,
                                                  ushort* __restrict__ C,
                                                  const float* __restrict__ bias,
                                                  int M, int N, int K, int nbn) {
  __shared__ alignas(16) ushort smem[65536];      // stage 128KB == C-tile 128KB
  ushort* const As0 = smem;
  ushort* const Bs0 = smem + 2 * 256 * 64;

  const int cpx = gridDim.x >> 3;
  const int wg = ((int)blockIdx.x & 7) * cpx + ((int)blockIdx.x >> 3);
  const int bm = wg / nbn, bn = wg % nbn;

  const int t = threadIdx.x;
  const int l = t & 63, w = t >> 6;
  const int wm = w >> 2, wn = w & 3;
  const int r = l & 15, kq = l >> 4;

  const size_t a0 = (size_t)bm * 256 * K;
  const size_t b0 = (size_t)bn * 256 * K;

  const int srow = t >> 3;
  const int sslot = (t & 7) ^ (srow & 7);
  const ushort* gA16 = (const ushort*)Aptr + a0 + (size_t)srow * K + sslot * 8;
  const float*  gAf  = (const float*)Aptr + a0 + (size_t)srow * K + sslot * 8;
  const ushort* gB = Bt + b0 + (size_t)srow * K + sslot * 8;
  const int lboff = w * 1024 + l * 16;

  f32x4 acc[8][4] = {};
  const int NKT = K >> 6;
  float4 areg[4][2];

#define STGA(buf, kt, u) \
  gload16(gA16 + (size_t)((u) * 64) * K + (size_t)(kt) * 64, \
          (char*)(As0 + (buf) * 256 * 64) + (u) * 8192 + lboff)
#define STGB(buf, kt, u) \
  gload16(gB + (size_t)((u) * 64) * K + (size_t)(kt) * 64, \
          (char*)(Bs0 + (buf) * 256 * 64) + (u) * 8192 + lboff)
#define ALOAD(kt, u) \
  do { const float* gs_ = gAf + (size_t)((u) * 64) * K + (size_t)(kt) * 64; \
       areg[u][0] = *(const float4*)gs_; areg[u][1] = *(const float4*)(gs_ + 4); } while (0)
#define AWRITE(buf, u) \
  *(u16x8*)((char*)(As0 + (buf) * 256 * 64) + (u) * 8192 + lboff) = cvt8(areg[u][0], areg[u][1])

#define QUAD(ph)                                                               \
  do {                                                                         \
    _Pragma("unroll")                                                          \
    for (int ii = 0; ii < 2; ++ii) {                                           \
      bf16x8 aF[2];                                                            \
      const int rowa = wm * 128 + ((ph) * 2 + ii) * 16 + r;                    \
      _Pragma("unroll")                                                        \
      for (int ks = 0; ks < 2; ++ks) {                                         \
        const int j = (ks * 4 + kq) ^ (r & 7);                                 \
        aF[ks] = *(const bf16x8*)&pA[rowa * 64 + j * 8];                       \
      }                                                                        \
      __builtin_amdgcn_s_setprio(1);                                           \
      _Pragma("unroll")                                                        \
      for (int jn = 0; jn < 4; ++jn)                                           \
        _Pragma("unroll")                                                      \
        for (int ks = 0; ks < 2; ++ks)                                         \
          acc[(ph) * 2 + ii][jn] = __builtin_amdgcn_mfma_f32_16x16x32_bf16(    \
              aF[ks], bF[jn][ks], acc[(ph) * 2 + ii][jn], 0, 0, 0);            \
      __builtin_amdgcn_s_setprio(0);                                           \
    }                                                                          \
  } while (0)

  if constexpr (AF32) {
#pragma unroll
    for (int u = 0; u < 4; ++u) ALOAD(0, u);
    STGB(0, 0, 0); STGB(0, 0, 1); STGB(0, 0, 2); STGB(0, 0, 3);
#pragma unroll
    for (int u = 0; u < 4; ++u) AWRITE(0, u);
    if (NKT > 1) {
#pragma unroll
      for (int u = 0; u < 4; ++u) ALOAD(1, u);
    }
  } else {
    STGB(0, 0, 0); STGB(0, 0, 1); STGB(0, 0, 2); STGB(0, 0, 3);
    STGA(0, 0, 0); STGA(0, 0, 2); STGA(0, 0, 1); STGA(0, 0, 3);
  }

  for (int kt = 0; kt < NKT; ++kt) {
    const int cur = kt & 1, nxt = cur ^ 1;
    const bool hn = (kt + 1 < NKT);
    const ushort* pA = As0 + cur * 256 * 64;
    const ushort* pB = Bs0 + cur * 256 * 64;

    if (hn) { STGB(nxt, kt + 1, 0); STGB(nxt, kt + 1, 1); }
    if constexpr (AF32) {
      if (hn) asm volatile("s_waitcnt vmcnt(10) lgkmcnt(0)" ::: "memory");
      else    asm volatile("s_waitcnt vmcnt(0) lgkmcnt(0)" ::: "memory");
    } else {
      if (hn) asm volatile("s_waitcnt vmcnt(2)" ::: "memory");
      else    asm volatile("s_waitcnt vmcnt(0)" ::: "memory");
    }
    __builtin_amdgcn_s_barrier();
    asm volatile("" ::: "memory");
    bf16x8 bF[4][2];
#pragma unroll
    for (int jn = 0; jn < 4; ++jn) {
      const int rowb = wn * 64 + jn * 16 + r;
#pragma unroll
      for (int ks = 0; ks < 2; ++ks) {
        const int j = (ks * 4 + kq) ^ (r & 7);
        bF[jn][ks] = *(const bf16x8*)&pB[rowb * 64 + j * 8];
      }
    }
    QUAD(0);
    if (hn) { STGB(nxt, kt + 1, 2); STGB(nxt, kt + 1, 3); }
    QUAD(1);
    bf16x8 aFn[2][2];
#pragma unroll
    for (int ii = 0; ii < 2; ++ii) {
      const int rowa = wm * 128 + (4 + ii) * 16 + r;
#pragma unroll
      for (int ks = 0; ks < 2; ++ks) {
        const int j = (ks * 4 + kq) ^ (r & 7);
        aFn[ii][ks] = *(const bf16x8*)&pA[rowa * 64 + j * 8];
      }
    }
    if constexpr (AF32) {
      if (hn) { AWRITE(nxt, 0); AWRITE(nxt, 1); }
      if (kt + 2 < NKT) { ALOAD(kt + 2, 0); ALOAD(kt + 2, 1); }
    } else {
      if (hn) { STGA(nxt, kt + 1, 0); STGA(nxt, kt + 1, 2); }
    }
    asm volatile("" ::: "memory");
    __builtin_amdgcn_s_barrier();
    __builtin_amdgcn_s_setprio(1);
#pragma unroll
    for (int ii = 0; ii < 2; ++ii)
#pragma unroll
      for (int jn = 0; jn < 4; ++jn)
#pragma unroll
        for (int ks = 0; ks < 2; ++ks)
          acc[4 + ii][jn] = __builtin_amdgcn_mfma_f32_16x16x32_bf16(
              aFn[ii][ks], bF[jn][ks], acc[4 + ii][jn], 0, 0, 0);
    __builtin_amdgcn_s_setprio(0);
    if constexpr (AF32) {
      if (hn) { AWRITE(nxt, 2); AWRITE(nxt, 3); }
      if (kt + 2 < NKT) { ALOAD(kt + 2, 2); ALOAD(kt + 2, 3); }
    } else {
      if (hn) { STGA(nxt, kt + 1, 1); STGA(nxt, kt + 1, 3); }
    }
    QUAD(3);
  }
#undef STGA
#undef STGB
#undef ALOAD
#undef AWRITE
#undef QUAD

  asm volatile("s_waitcnt lgkmcnt(0) vmcnt(0)" ::: "memory");
  __builtin_amdgcn_s_barrier();

  const int q4 = (l >> 4) * 4;
  float bvj[4];
#pragma unroll
  for (int jn = 0; jn < 4; ++jn) {
    const int col = wn * 64 + jn * 16 + r;
    bvj[jn] = bias ? bias[bn * 256 + col] : 0.f;
  }
#pragma unroll
  for (int i = 0; i < 8; ++i) {
#pragma unroll
    for (int jn = 0; jn < 4; ++jn) {
      const int col = wn * 64 + jn * 16 + r;
      const int chunk = col >> 3;
#pragma unroll
      for (int q = 0; q < 4; ++q) {
        const int rowl = wm * 128 + i * 16 + q4 + q;
        const int pch = chunk ^ (rowl & 7);
        smem[rowl * 256 + pch * 8 + (col & 7)] = f2bf(acc[i][jn][q] + bvj[jn]);
      }
    }
  }
  __builtin_amdgcn_s_barrier();

  const int rrow0 = t >> 5;
  const int rch = t & 31;
#pragma unroll
  for (int p = 0; p < 16; ++p) {
    const int rowl = p * 16 + rrow0;
    const int pch = rch ^ (rowl & 7);
    u16x8 vv = *(const u16x8*)&smem[rowl * 256 + pch * 8];
    const size_t grow = (size_t)(bm * 256 + rowl);
    *(u16x8*)&C[grow * N + bn * 256 + rch * 8] = vv;
  }
}

// ---------------------------------------------------------------------------
// gemm8p (GEMM2): m201-faithful half-tile schedule.
// LDS: A slots [buf][half] 4x16KB at sm+0; B slots 4x16KB at sm+64KB.
// Wave (wm,wn) reads only A-half[wm] and B-half[wn>>1] of each tile.
// Per K-tile kt (buf=kt&1), 4 phases, each = {pre-barrier ds_reads + stage,
// barrier, lgkmcnt(0), setprio+16 MFMA+setprio, barrier}:
//  ph0: read bF(8)+aF q0(4); stage A-h0(kt+1) -> A[nxt]   (A[nxt] readers
//       sealed: tile kt-1 finished at ph3(kt-1) second barrier)
//  ph1: read aF q1; stage A-h1(kt+1)
//  ph2: read aF q2; stage B-h0(kt+2) -> B[cur]  (B[cur] read ONLY at ph0(kt),
//       those reads retired via lgkmcnt before ph0's 2nd barrier; collective
//       barriers ph1 ensure all waves past it before any wave stages)
//  ph3: read aF q3; stage B-h1(kt+2); vmcnt(4) = allow only B(kt+2)'s 4 in
//       flight -> A(kt+1) [2-3 phase slack] and B(kt+1) [5-6 phase slack]
//       proven landed; barrier publishes -> ph0(kt+1)'s pre-barrier reads
//       are >=1 barrier after publish (latency hidden under barrier waits).
//       Tails: kt+2>=NKT -> vmcnt(0).
// Prologue: B(0),A(0),B(1) staged; vmcnt(4) (B(1) in flight); barrier.
// Drift-safety: every read retires via its phase's lgkmcnt before that
// phase's 2nd barrier; every stage is issued after a 2nd barrier that
// collectively follows the reads it could clobber.
// ---------------------------------------------------------------------------
__global__ __launch_bounds__(512, 2) void gemm8p(const ushort* __restrict__ A,
                                                 const ushort* __restrict__ Bt,
                                                 ushort* __restrict__ C,
                                                 const float* __restrict__ bias,
                                                 int M, int N, int K, int nbn) {
  __shared__ alignas(16) ushort smem[65536];      // 128 KiB
  char* const sm = (char*)smem;

  const int cpx = gridDim.x >> 3;
  const int wg = ((int)blockIdx.x & 7) * cpx + ((int)blockIdx.x >> 3);
  const int bm = wg / nbn, bn = wg % nbn;

  const int t = threadIdx.x;
  const int l = t & 63, w = t >> 6;
  const int wm = w >> 2, wn = w & 3;              // wave grid 2(M) x 4(N)
  const int r = l & 15, kq = l >> 4;
  const int bh = wn >> 1;                         // B half this wave reads
  const int lbrow0 = (wn & 1) * 64;               // row base within B half

  const size_t a0 = (size_t)bm * 256 * K;
  const size_t b0 = (size_t)bn * 256 * K;

  const int srow = t >> 3;                        // 0..63
  const int sslot = (t & 7) ^ (srow & 7);
  const ushort* gA = A + a0 + (size_t)srow * K + sslot * 8;
  const ushort* gB = Bt + b0 + (size_t)srow * K + sslot * 8;
  const int lboff = w * 1024 + l * 16;

  f32x4 acc[8][4] = {};
  const int NKT = K >> 6;

#define STG_A(buf, half, kt) do {                                              \
    gload16(gA + (size_t)((half) * 128) * K + (size_t)(kt) * 64,               \
            sm + ((buf) * 2 + (half)) * 16384 + lboff);                        \
    gload16(gA + (size_t)((half) * 128 + 64) * K + (size_t)(kt) * 64,          \
            sm + ((buf) * 2 + (half)) * 16384 + 8192 + lboff);                 \
  } while (0)
#define STG_B(buf, half, kt) do {                                              \
    gload16(gB + (size_t)((half) * 128) * K + (size_t)(kt) * 64,               \
            sm + 65536 + ((buf) * 2 + (half)) * 16384 + lboff);                \
    gload16(gB + (size_t)((half) * 128 + 64) * K + (size_t)(kt) * 64,          \
            sm + 65536 + ((buf) * 2 + (half)) * 16384 + 8192 + lboff);         \
  } while (0)

#define READQ(ph)                                                              \
  { _Pragma("unroll")                                                          \
    for (int ii = 0; ii < 2; ++ii) {                                           \
      const int la = ((ph) * 2 + ii) * 16 + r;                                 \
      _Pragma("unroll")                                                        \
      for (int ks = 0; ks < 2; ++ks) {                                         \
        const int j = (ks * 4 + kq) ^ (r & 7);                                 \
        aF[ii][ks] = *(const bf16x8*)(pA + la * 64 + j * 8);                   \
      }                                                                        \
    } }

#define MMAQ(ph)                                                               \
  __builtin_amdgcn_s_setprio(1);                                               \
  _Pragma("unroll")                                                            \
  for (int ii = 0; ii < 2; ++ii)                                               \
    _Pragma("unroll")                                                          \
    for (int jn = 0; jn < 4; ++jn)                                             \
      _Pragma("unroll")                                                        \
      for (int ks = 0; ks < 2; ++ks)                                           \
        acc[(ph) * 2 + ii][jn] = __builtin_amdgcn_mfma_f32_16x16x32_bf16(      \
            aF[ii][ks], bF[jn][ks], acc[(ph) * 2 + ii][jn], 0, 0, 0);          \
  __builtin_amdgcn_s_setprio(0);

#define PH_SYNC                                                                \
  asm volatile("" ::: "memory");                                               \
  __builtin_amdgcn_s_barrier();                                                \
  asm volatile("s_waitcnt lgkmcnt(0)" ::: "memory");

#define PH_END                                                                 \
  asm volatile("" ::: "memory");                                               \
  __builtin_amdgcn_s_barrier();

  // prologue: B(0) halves, A(0) halves, B(1) halves; publish tile 0
  STG_B(0, 0, 0); STG_B(0, 1, 0);
  STG_A(0, 0, 0); STG_A(0, 1, 0);
  STG_B(1, 0, 1); STG_B(1, 1, 1);
  asm volatile("s_waitcnt vmcnt(4)" ::: "memory");   // B(1) stays in flight
  __builtin_amdgcn_s_barrier();

  for (int kt = 0; kt < NKT; ++kt) {
    const int cur = kt & 1, nxt = cur ^ 1;
    const ushort* pA = (const ushort*)(sm + (cur * 2 + wm) * 16384);
    const ushort* pB = (const ushort*)(sm + 65536 + (cur * 2 + bh) * 16384);
    bf16x8 bF[4][2];
    bf16x8 aF[2][2];

    // ---- phase 0 ----
#pragma unroll
    for (int jn = 0; jn < 4; ++jn) {
      const int rowb = lbrow0 + jn * 16 + r;
#pragma unroll
      for (int ks = 0; ks < 2; ++ks) {
        const int j = (ks * 4 + kq) ^ (r & 7);
        bF[jn][ks] = *(const bf16x8*)(pB + rowb * 64 + j * 8);
      }
    }
    READQ(0);
    if (kt + 1 < NKT) STG_A(nxt, 0, kt + 1);
    PH_SYNC;
    MMAQ(0);
    PH_END;
    // ---- phase 1 ----
    READQ(1);
    if (kt + 1 < NKT) STG_A(nxt, 1, kt + 1);
    PH_SYNC;
    MMAQ(1);
    PH_END;
    // ---- phase 2 ----
    READQ(2);
    if (kt + 2 < NKT) STG_B(cur, 0, kt + 2);
    PH_SYNC;
    MMAQ(2);
    PH_END;
    // ---- phase 3 (publish next tile) ----
    READQ(3);
    if (kt + 2 < NKT) {
      STG_B(cur, 1, kt + 2);
      asm volatile("s_waitcnt vmcnt(4)" ::: "memory");
    } else {
      asm volatile("s_waitcnt vmcnt(0)" ::: "memory");
    }
    PH_SYNC;
    MMAQ(3);
    PH_END;
  }
#undef STG_A
#undef STG_B
#undef READQ
#undef MMAQ
#undef PH_SYNC
#undef PH_END

  // ---- epilogue via LDS: swizzled scatter, then coalesced 16B stores ----
  asm volatile("s_waitcnt lgkmcnt(0) vmcnt(0)" ::: "memory");
  __builtin_amdgcn_s_barrier();

  const int q4 = (l >> 4) * 4;
  float bvj[4];
#pragma unroll
  for (int jn = 0; jn < 4; ++jn) {
    const int col = wn * 64 + jn * 16 + r;
    bvj[jn] = bias ? bias[bn * 256 + col] : 0.f;
  }
#pragma unroll
  for (int i = 0; i < 8; ++i) {
#pragma unroll
    for (int jn = 0; jn < 4; ++jn) {
      const int col = wn * 64 + jn * 16 + r;
      const int chunk = col >> 3;
#pragma unroll
      for (int q = 0; q < 4; ++q) {
        const int rowl = wm * 128 + i * 16 + q4 + q;
        const int pch = chunk ^ (rowl & 7);
        smem[rowl * 256 + pch * 8 + (col & 7)] = f2bf(acc[i][jn][q] + bvj[jn]);
      }
    }
  }
  __builtin_amdgcn_s_barrier();

  const int rrow0 = t >> 5;
  const int rch = t & 31;
#pragma unroll
  for (int p = 0; p < 16; ++p) {
    const int rowl = p * 16 + rrow0;
    const int pch = rch ^ (rowl & 7);
    u16x8 vv = *(const u16x8*)&smem[rowl * 256 + pch * 8];
    const size_t grow = (size_t)(bm * 256 + rowl);
    *(u16x8*)&C[grow * N + bn * 256 + rch * 8] = vv;
  }
}

// ---------------------------------------------------------------------------
// Scan kernels. lin[row, 2048] (bf16): [theta | retain_logit | inp_r | inp_i]
// ---------------------------------------------------------------------------
__global__ __launch_bounds__(256) void scan_k1(const ushort* __restrict__ lin,
                                               float4* __restrict__ agg) {
  int bd = blockIdx.x * 256 + threadIdx.x;
  int c  = blockIdx.y;
  int b  = bd >> 9, d = bd & 511;
  const ushort* base = lin + ((size_t)b * 4096 + (size_t)c * 32) * 2048;
  float cth = 0.f, cbr = 0.f, cbi = 0.f;
  float cm = 1.f, cs = 1.f, sn = 0.f;
#pragma unroll 4
  for (int t = 0; t < 32; ++t) {
    const ushort* row = base + (size_t)t * 2048;
    float th = bf2f(row[d]);
    float z  = bf2f(row[512 + d]);
    float ir = bf2f(row[1024 + d]);
    float ii = bf2f(row[1536 + d]);
    float rt = __fdividef(1.f, 1.f + __expf(-z));
    cm *= fmaxf(rt, 1e-6f);
    cth += th;
    float s_, c_;
    __sincosf(cth, &s_, &c_);
    float im = __fdividef(1.f, fmaxf(cm, 1e-8f));
    float invr = im * c_, invi = -im * s_;
    float drive = 1.f - rt;
    float br_ = drive * ir, bi_ = drive * ii;
    cbr += invr * br_ - invi * bi_;
    cbi += invr * bi_ + invi * br_;
    cs = c_; sn = s_;
  }
  agg[(size_t)c * 2048 + bd] = make_float4(cm * cs, cm * sn, cbr, cbi);
}

__global__ __launch_bounds__(256) void scan_k2(const float4* __restrict__ agg,
                                               float2* __restrict__ h0) {
  int bd = blockIdx.x * 256 + threadIdx.x;
  float hr = 0.f, hi = 0.f;
  for (int cg = 0; cg < 16; ++cg) {
    float4 a[8];
#pragma unroll
    for (int u = 0; u < 8; ++u) a[u] = agg[(size_t)(cg * 8 + u) * 2048 + bd];
#pragma unroll
    for (int u = 0; u < 8; ++u) {
      h0[(size_t)(cg * 8 + u) * 2048 + bd] = make_float2(hr, hi);
      float tr = hr + a[u].z, ti = hi + a[u].w;
      hr = a[u].x * tr - a[u].y * ti;
      hi = a[u].x * ti + a[u].y * tr;
    }
  }
}

__global__ __launch_bounds__(256) void scan_k3(const ushort* __restrict__ lin,
                                               const float2* __restrict__ h0,
                                               ushort* __restrict__ outb) {
  int bd = blockIdx.x * 256 + threadIdx.x;
  int c  = blockIdx.y;
  int b  = bd >> 9, d = bd & 511;
  const ushort* base = lin + ((size_t)b * 4096 + (size_t)c * 32) * 2048;
  float2 h = h0[(size_t)c * 2048 + bd];
  float cth = 0.f, cbr = 0.f, cbi = 0.f, cm = 1.f;
#pragma unroll 4
  for (int t = 0; t < 32; ++t) {
    const ushort* row = base + (size_t)t * 2048;
    float th = bf2f(row[d]);
    float z  = bf2f(row[512 + d]);
    float ir = bf2f(row[1024 + d]);
    float ii = bf2f(row[1536 + d]);
    float rt = __fdividef(1.f, 1.f + __expf(-z));
    cm *= fmaxf(rt, 1e-6f);
    cth += th;
    float s_, c_;
    __sincosf(cth, &s_, &c_);
    float im = __fdividef(1.f, fmaxf(cm, 1e-8f));
    float invr = im * c_, invi = -im * s_;
    float drive = 1.f - rt;
    float br_ = drive * ir, bi_ = drive * ii;
    cbr += invr * br_ - invi * bi_;
    cbi += invr * bi_ + invi * br_;
    float ar = cm * c_, ai = cm * s_;
    float tr = h.x + cbr, ti = h.y + cbi;
    float orr = ar * tr - ai * ti;
    float oii = ar * ti + ai * tr;
    size_t rowo = ((size_t)b * 4096 + (size_t)c * 32 + t) * 1024;
    outb[rowo + d] = f2bf(orr);
    outb[rowo + 512 + d] = f2bf(oii);
  }
}

// ---------------------------------------------------------------------------
// LayerNorm, one WAVE per row (4 rows/block). y = yb(bf16) + x(f32 residual).
// ---------------------------------------------------------------------------
__global__ __launch_bounds__(256) void ln_k(const ushort* __restrict__ yb,
                                            const float* __restrict__ x,
                                            const float* __restrict__ gamma,
                                            const float* __restrict__ beta,
                                            float* __restrict__ out) {
  const int lane = threadIdx.x & 63;
  const size_t row = (size_t)blockIdx.x * 4 + (threadIdx.x >> 6);
  const ushort* yr = yb + row * 1024;
  const float* xr = x + row * 1024;
  float v[4][4];
  float s = 0.f, s2 = 0.f;
#pragma unroll
  for (int q = 0; q < 4; ++q) {
    ushort4 uy = *(const ushort4*)(yr + q * 256 + lane * 4);
    float4 fx = *(const float4*)(xr + q * 256 + lane * 4);
    v[q][0] = bf2f(uy.x) + fx.x;
    v[q][1] = bf2f(uy.y) + fx.y;
    v[q][2] = bf2f(uy.z) + fx.z;
    v[q][3] = bf2f(uy.w) + fx.w;
#pragma unroll
    for (int j = 0; j < 4; ++j) { s += v[q][j]; s2 += v[q][j] * v[q][j]; }
  }
#pragma unroll
  for (int off = 32; off > 0; off >>= 1) {
    s  += __shfl_xor(s, off);
    s2 += __shfl_xor(s2, off);
  }
  const float mu = s * (1.f / 1024.f);
  const float rstd = rsqrtf(s2 * (1.f / 1024.f) - mu * mu + 1e-5f);
#pragma unroll
  for (int q = 0; q < 4; ++q) {
    float4 gv = *(const float4*)(gamma + q * 256 + lane * 4);
    float4 bv = *(const float4*)(beta + q * 256 + lane * 4);
    float4 o;
    o.x = (v[q][0] - mu) * rstd * gv.x + bv.x;
    o.y = (v[q][1] - mu) * rstd * gv.y + bv.y;
    o.z = (v[q][2] - mu) * rstd * gv.z + bv.z;
    o.w = (v[q][3] - mu) * rstd * gv.w + bv.w;
    *(float4*)(out + row * 1024 + q * 256 + lane * 4) = o;
  }
}

// ---------------------------------------------------------------------------
extern "C" void kernel_launch(void* const* d_in, const int* in_sizes, int n_in,
                              void* d_out, int out_size, void* d_ws, size_t ws_size,
                              hipStream_t stream) {
  (void)in_sizes; (void)n_in; (void)out_size; (void)ws_size;
  const float* x  = (const float*)d_in[0];
  const float* Wt = (const float*)d_in[1];
  const float* bt = (const float*)d_in[2];
  const float* Wr = (const float*)d_in[3];
  const float* br = (const float*)d_in[4];
  const float* Wi = (const float*)d_in[5];
  const float* bi = (const float*)d_in[6];
  const float* Wo = (const float*)d_in[7];
  const float* bo = (const float*)d_in[8];
  const float* gamma = (const float*)d_in[9];
  const float* beta  = (const float*)d_in[10];

  char* ws = (char*)d_ws;
  ushort* wcat_t = (ushort*)(ws);                      //  4 MiB: [2048][1024] bf16
  ushort* wo_t   = (ushort*)(ws + ((size_t)4  << 20)); //  2 MiB: [1024][1024] bf16
  float*  bcat   = (float*) (ws + ((size_t)6  << 20)); //  8 KiB
  float4* agg    = (float4*)(ws + ((size_t)8  << 20)); //  4 MiB: [128][2048]
  float2* h0     = (float2*)(ws + ((size_t)12 << 20)); //  2 MiB: [128][2048]
  ushort* outb   = (ushort*)(ws + ((size_t)48 << 20)); // 32 MiB: scan out bf16
  ushort* linb   = (ushort*)(ws + ((size_t)80 << 20)); // 64 MiB: lin bf16
  ushort* yb     = (ushort*)(ws + ((size_t)80 << 20)); // 32 MiB: y bf16 (overlays dead linb)

  // weight prep (fused) + bias pack
  tconv_all<<<dim3(32, 32, 4), dim3(32, 8), 0, stream>>>(Wt, Wr, Wi, Wo, wcat_t, wo_t);
  pack_bias<<<8, 256, 0, stream>>>(bt, br, bi, bcat);

  // lin(bf16) = x(f32, converted in-kernel) @ [Wt|Wr|Wi] + [bt|br|bi]
  gemm256<true><<<512, 512, 0, stream>>>(x, wcat_t, linb, bcat, 16384, 2048, 1024, 8);

  // chunked complex scan
  scan_k1<<<dim3(8, 128), 256, 0, stream>>>(linb, agg);
  scan_k2<<<8, 256, 0, stream>>>(agg, h0);
  scan_k3<<<dim3(8, 128), 256, 0, stream>>>(linb, h0, outb);

  // yb(bf16) = out @ Wo + bo   (256 blocks, 1/CU) — m201-faithful schedule
  gemm8p<<<256, 512, 0, stream>>>(outb, wo_t, yb, bo, 16384, 1024, 1024, 4);

  // layernorm(yb + x) -> d_out   (one wave per row, f32 residual)
  ln_k<<<4096, 256, 0, stream>>>(yb, x, gamma, beta, (float*)d_out);
}

// Round 15
// 193.801 us; speedup vs baseline: 1.0056x; 1.0056x over previous
//
#include <hip/hip_runtime.h>
#include <cstdint>

// ---------------------------------------------------------------------------
// RotationScan: theta/retain/inp GEMM -> chunked complex scan -> out GEMM -> LN
// B=4 T=4096 D=1024 SD=512 CHUNK=32
// r15 = r13 (session-best structure) + GEMM2 reverted to gemm256<false>
// (r14's gemm8p was neutral, 5th schedule-family null) + residual add fused
// into GEMM2's coalesced epilogue readback (ln_k 160->96 MB).
// ---------------------------------------------------------------------------

typedef __bf16 bf16x8 __attribute__((ext_vector_type(8)));
typedef float  f32x4  __attribute__((ext_vector_type(4)));
typedef ushort u16x8  __attribute__((ext_vector_type(8)));

#define AS1 __attribute__((address_space(1)))
#define AS3 __attribute__((address_space(3)))

__device__ __forceinline__ void gload16(const void* g, void* l) {
  __builtin_amdgcn_global_load_lds((const AS1 void*)g, (AS3 void*)l, 16, 0, 0);
}

__device__ __forceinline__ ushort f2bf(float f) {
  union { float f; uint32_t u; } v; v.f = f;
  uint32_t u = v.u;
  uint32_t r = u + 0x7FFFu + ((u >> 16) & 1u);   // RNE
  return (ushort)(r >> 16);
}
__device__ __forceinline__ float bf2f(ushort u) {
  union { uint32_t x; float f; } v; v.x = (uint32_t)u << 16; return v.f;
}
__device__ __forceinline__ u16x8 cvt8(float4 a, float4 b) {
  u16x8 o;
  o[0] = f2bf(a.x); o[1] = f2bf(a.y); o[2] = f2bf(a.z); o[3] = f2bf(a.w);
  o[4] = f2bf(b.x); o[5] = f2bf(b.y); o[6] = f2bf(b.z); o[7] = f2bf(b.w);
  return o;
}

// ---------------------------------------------------------------------------
// Fused transpose + f32->bf16 for all 4 weights (one launch).
// ---------------------------------------------------------------------------
__global__ __launch_bounds__(256) void tconv_all(const float* __restrict__ Wt,
                                                 const float* __restrict__ Wr,
                                                 const float* __restrict__ Wi,
                                                 const float* __restrict__ Wo,
                                                 ushort* __restrict__ wcat,
                                                 ushort* __restrict__ wot) {
  const int z = blockIdx.z;
  if (z < 2 && blockIdx.x >= 16) return;          // C=512 weights: 16 col-blocks
  const float* src = (z == 0) ? Wt : (z == 1) ? Wr : (z == 2) ? Wi : Wo;
  const int C = (z < 2) ? 512 : 1024;
  const int row_off = (z == 0) ? 0 : (z == 1) ? 512 : (z == 2) ? 1024 : 0;
  ushort* dst = (z == 3) ? wot : wcat;

  __shared__ float tile[32][33];
  int tx = threadIdx.x, ty = threadIdx.y;
  int rb = blockIdx.y * 32, cb = blockIdx.x * 32;
#pragma unroll
  for (int yy = 0; yy < 4; ++yy) {
    int r = rb + ty + yy * 8;
    tile[ty + yy * 8][tx] = src[(size_t)r * C + cb + tx];
  }
  __syncthreads();
#pragma unroll
  for (int yy = 0; yy < 4; ++yy) {
    int c = cb + ty + yy * 8;
    dst[(size_t)(row_off + c) * 1024 + rb + tx] = f2bf(tile[tx][ty + yy * 8]);
  }
}

__global__ __launch_bounds__(256) void pack_bias(const float* __restrict__ bt,
                                                 const float* __restrict__ br,
                                                 const float* __restrict__ bi,
                                                 float* __restrict__ bcat) {
  int i = blockIdx.x * 256 + threadIdx.x;          // 0..2047
  bcat[i] = (i < 512) ? bt[i] : (i < 1024 ? br[i - 512] : bi[i - 1024]);
}

// ---------------------------------------------------------------------------
// 256x256 tile, BK=64, 8 waves (2Mx4N), double-buffered 128 KiB LDS.
// 16x16x32 MFMA + chunk^(row&7) swizzle (verified conflict-free).
// r11/r13 schedule (session-best): single publish vmcnt per K-tile, QUAD2
// pre-read before the WAR-spacer barrier.
//
// AF32=false (GEMM2): 8 gload_lds/K-tile, P0 wait vmcnt(2) [tail 0].
// AF32=true (GEMM1): A reg-staged from f32, 1-tile-deep prefetch:
//   P0 wait vmcnt(10) lgkmcnt(0): newest 10 = {B0B1(kt+1), A(kt+1) 8 loads
//   from P2/P3(kt-1)} -> B(kt) landed; lgkmcnt publishes kt-1's A ds_writes.
//   P2/P3: AWRITE(kt+1) then ALOAD(kt+2) (full-tile HBM slack).
//
// Epilogue: C-tile -> LDS 16B-chunk XOR swizzle -> coalesced u16x8 stores.
// If resid != nullptr (GEMM2): per-iteration coalesced float4x2 read of the
// residual with depth-4 static-index rolling prefetch, add before bf16 store
// (plain C++ loads AFTER the epilogue vmcnt(0) -> no ledger interaction).
// ---------------------------------------------------------------------------
template <bool AF32>
__global__ __launch_bounds__(512, 2) void gemm256(const void* __restrict__ Aptr,
                                                  const ushort* __restrict__ Bt,
                                                  ushort* __restrict__ C,
                                                  const float* __restrict__ bias,
                                                  const float* __restrict__ resid,
                                                  int M, int N, int K, int nbn) {
  __shared__ alignas(16) ushort smem[65536];      // stage 128KB == C-tile 128KB
  ushort* const As0 = smem;
  ushort* const Bs0 = smem + 2 * 256 * 64;

  const int cpx = gridDim.x >> 3;
  const int wg = ((int)blockIdx.x & 7) * cpx + ((int)blockIdx.x >> 3);
  const int bm = wg / nbn, bn = wg % nbn;

  const int t = threadIdx.x;
  const int l = t & 63, w = t >> 6;
  const int wm = w >> 2, wn = w & 3;
  const int r = l & 15, kq = l >> 4;

  const size_t a0 = (size_t)bm * 256 * K;
  const size_t b0 = (size_t)bn * 256 * K;

  const int srow = t >> 3;
  const int sslot = (t & 7) ^ (srow & 7);
  const ushort* gA16 = (const ushort*)Aptr + a0 + (size_t)srow * K + sslot * 8;
  const float*  gAf  = (const float*)Aptr + a0 + (size_t)srow * K + sslot * 8;
  const ushort* gB = Bt + b0 + (size_t)srow * K + sslot * 8;
  const int lboff = w * 1024 + l * 16;

  f32x4 acc[8][4] = {};
  const int NKT = K >> 6;
  float4 areg[4][2];

#define STGA(buf, kt, u) \
  gload16(gA16 + (size_t)((u) * 64) * K + (size_t)(kt) * 64, \
          (char*)(As0 + (buf) * 256 * 64) + (u) * 8192 + lboff)
#define STGB(buf, kt, u) \
  gload16(gB + (size_t)((u) * 64) * K + (size_t)(kt) * 64, \
          (char*)(Bs0 + (buf) * 256 * 64) + (u) * 8192 + lboff)
#define ALOAD(kt, u) \
  do { const float* gs_ = gAf + (size_t)((u) * 64) * K + (size_t)(kt) * 64; \
       areg[u][0] = *(const float4*)gs_; areg[u][1] = *(const float4*)(gs_ + 4); } while (0)
#define AWRITE(buf, u) \
  *(u16x8*)((char*)(As0 + (buf) * 256 * 64) + (u) * 8192 + lboff) = cvt8(areg[u][0], areg[u][1])

#define QUAD(ph)                                                               \
  do {                                                                         \
    _Pragma("unroll")                                                          \
    for (int ii = 0; ii < 2; ++ii) {                                           \
      bf16x8 aF[2];                                                            \
      const int rowa = wm * 128 + ((ph) * 2 + ii) * 16 + r;                    \
      _Pragma("unroll")                                                        \
      for (int ks = 0; ks < 2; ++ks) {                                         \
        const int j = (ks * 4 + kq) ^ (r & 7);                                 \
        aF[ks] = *(const bf16x8*)&pA[rowa * 64 + j * 8];                       \
      }                                                                        \
      __builtin_amdgcn_s_setprio(1);                                           \
      _Pragma("unroll")                                                        \
      for (int jn = 0; jn < 4; ++jn)                                           \
        _Pragma("unroll")                                                      \
        for (int ks = 0; ks < 2; ++ks)                                         \
          acc[(ph) * 2 + ii][jn] = __builtin_amdgcn_mfma_f32_16x16x32_bf16(    \
              aF[ks], bF[jn][ks], acc[(ph) * 2 + ii][jn], 0, 0, 0);            \
      __builtin_amdgcn_s_setprio(0);                                           \
    }                                                                          \
  } while (0)

  if constexpr (AF32) {
#pragma unroll
    for (int u = 0; u < 4; ++u) ALOAD(0, u);
    STGB(0, 0, 0); STGB(0, 0, 1); STGB(0, 0, 2); STGB(0, 0, 3);
#pragma unroll
    for (int u = 0; u < 4; ++u) AWRITE(0, u);
    if (NKT > 1) {
#pragma unroll
      for (int u = 0; u < 4; ++u) ALOAD(1, u);
    }
  } else {
    STGB(0, 0, 0); STGB(0, 0, 1); STGB(0, 0, 2); STGB(0, 0, 3);
    STGA(0, 0, 0); STGA(0, 0, 2); STGA(0, 0, 1); STGA(0, 0, 3);
  }

  for (int kt = 0; kt < NKT; ++kt) {
    const int cur = kt & 1, nxt = cur ^ 1;
    const bool hn = (kt + 1 < NKT);
    const ushort* pA = As0 + cur * 256 * 64;
    const ushort* pB = Bs0 + cur * 256 * 64;

    // ---------------- phase 0 (publish) ----------------
    if (hn) { STGB(nxt, kt + 1, 0); STGB(nxt, kt + 1, 1); }
    if constexpr (AF32) {
      if (hn) asm volatile("s_waitcnt vmcnt(10) lgkmcnt(0)" ::: "memory");
      else    asm volatile("s_waitcnt vmcnt(0) lgkmcnt(0)" ::: "memory");
    } else {
      if (hn) asm volatile("s_waitcnt vmcnt(2)" ::: "memory");
      else    asm volatile("s_waitcnt vmcnt(0)" ::: "memory");
    }
    __builtin_amdgcn_s_barrier();
    asm volatile("" ::: "memory");
    bf16x8 bF[4][2];
#pragma unroll
    for (int jn = 0; jn < 4; ++jn) {
      const int rowb = wn * 64 + jn * 16 + r;
#pragma unroll
      for (int ks = 0; ks < 2; ++ks) {
        const int j = (ks * 4 + kq) ^ (r & 7);
        bF[jn][ks] = *(const bf16x8*)&pB[rowb * 64 + j * 8];
      }
    }
    QUAD(0);
    // ---------------- phase 1 ----------------
    if (hn) { STGB(nxt, kt + 1, 2); STGB(nxt, kt + 1, 3); }
    QUAD(1);
    // pre-read phase-2 fragments (As[cur] published at P0 barrier -> legal)
    bf16x8 aFn[2][2];
#pragma unroll
    for (int ii = 0; ii < 2; ++ii) {
      const int rowa = wm * 128 + (4 + ii) * 16 + r;
#pragma unroll
      for (int ks = 0; ks < 2; ++ks) {
        const int j = (ks * 4 + kq) ^ (r & 7);
        aFn[ii][ks] = *(const bf16x8*)&pA[rowa * 64 + j * 8];
      }
    }
    // ---------------- phase 2 (WAR spacer) ----------------
    if constexpr (AF32) {
      if (hn) { AWRITE(nxt, 0); AWRITE(nxt, 1); }
      if (kt + 2 < NKT) { ALOAD(kt + 2, 0); ALOAD(kt + 2, 1); }
    } else {
      if (hn) { STGA(nxt, kt + 1, 0); STGA(nxt, kt + 1, 2); }
    }
    asm volatile("" ::: "memory");
    __builtin_amdgcn_s_barrier();
    __builtin_amdgcn_s_setprio(1);
#pragma unroll
    for (int ii = 0; ii < 2; ++ii)
#pragma unroll
      for (int jn = 0; jn < 4; ++jn)
#pragma unroll
        for (int ks = 0; ks < 2; ++ks)
          acc[4 + ii][jn] = __builtin_amdgcn_mfma_f32_16x16x32_bf16(
              aFn[ii][ks], bF[jn][ks], acc[4 + ii][jn], 0, 0, 0);
    __builtin_amdgcn_s_setprio(0);
    // ---------------- phase 3 ----------------
    if constexpr (AF32) {
      if (hn) { AWRITE(nxt, 2); AWRITE(nxt, 3); }
      if (kt + 2 < NKT) { ALOAD(kt + 2, 2); ALOAD(kt + 2, 3); }
    } else {
      if (hn) { STGA(nxt, kt + 1, 1); STGA(nxt, kt + 1, 3); }
    }
    QUAD(3);
  }
#undef STGA
#undef STGB
#undef ALOAD
#undef AWRITE
#undef QUAD

  // ---- epilogue via LDS: swizzled scatter, then coalesced 16B stores ----
  asm volatile("s_waitcnt lgkmcnt(0) vmcnt(0)" ::: "memory");
  __builtin_amdgcn_s_barrier();                   // all waves done with stage LDS

  const int q4 = (l >> 4) * 4;
  float bvj[4];
#pragma unroll
  for (int jn = 0; jn < 4; ++jn) {
    const int col = wn * 64 + jn * 16 + r;
    bvj[jn] = bias ? bias[bn * 256 + col] : 0.f;
  }
#pragma unroll
  for (int i = 0; i < 8; ++i) {
#pragma unroll
    for (int jn = 0; jn < 4; ++jn) {
      const int col = wn * 64 + jn * 16 + r;
      const int chunk = col >> 3;
#pragma unroll
      for (int q = 0; q < 4; ++q) {
        const int rowl = wm * 128 + i * 16 + q4 + q;
        const int pch = chunk ^ (rowl & 7);
        smem[rowl * 256 + pch * 8 + (col & 7)] = f2bf(acc[i][jn][q] + bvj[jn]);
      }
    }
  }
  __builtin_amdgcn_s_barrier();

  const int rrow0 = t >> 5;                       // 0..15
  const int rch = t & 31;                         // logical 16B chunk
  if (resid == nullptr) {
#pragma unroll
    for (int p = 0; p < 16; ++p) {
      const int rowl = p * 16 + rrow0;
      const int pch = rch ^ (rowl & 7);
      u16x8 vv = *(const u16x8*)&smem[rowl * 256 + pch * 8];
      const size_t grow = (size_t)(bm * 256 + rowl);
      *(u16x8*)&C[grow * N + bn * 256 + rch * 8] = vv;
    }
  } else {
    // depth-4 rolling prefetch of the residual (static indices: full unroll)
    f32x4 xa[4][2];
#pragma unroll
    for (int pp = 0; pp < 3; ++pp) {
      const int rowl = pp * 16 + rrow0;
      const float* xp = resid + (size_t)(bm * 256 + rowl) * N + bn * 256 + rch * 8;
      xa[pp][0] = *(const f32x4*)xp;
      xa[pp][1] = *(const f32x4*)(xp + 4);
    }
#pragma unroll
    for (int p = 0; p < 16; ++p) {
      if (p + 3 < 16) {
        const int rowl = (p + 3) * 16 + rrow0;
        const float* xp = resid + (size_t)(bm * 256 + rowl) * N + bn * 256 + rch * 8;
        xa[(p + 3) & 3][0] = *(const f32x4*)xp;
        xa[(p + 3) & 3][1] = *(const f32x4*)(xp + 4);
      }
      const int rowl = p * 16 + rrow0;
      const int pch = rch ^ (rowl & 7);
      u16x8 vv = *(const u16x8*)&smem[rowl * 256 + pch * 8];
      u16x8 ov;
#pragma unroll
      for (int j = 0; j < 4; ++j) ov[j] = f2bf(bf2f(vv[j]) + xa[p & 3][0][j]);
#pragma unroll
      for (int j = 0; j < 4; ++j) ov[4 + j] = f2bf(bf2f(vv[4 + j]) + xa[p & 3][1][j]);
      const size_t grow = (size_t)(bm * 256 + rowl);
      *(u16x8*)&C[grow * N + bn * 256 + rch * 8] = ov;
    }
  }
}

// ---------------------------------------------------------------------------
// Scan kernels. lin[row, 2048] (bf16): [theta | retain_logit | inp_r | inp_i]
// cum_mag as running product (== exp(cumsum(log(clip(rt,1e-6)))) within fp32
// noise); the 1e-8 clip on the inverse is preserved exactly.
// ---------------------------------------------------------------------------
__global__ __launch_bounds__(256) void scan_k1(const ushort* __restrict__ lin,
                                               float4* __restrict__ agg) {
  int bd = blockIdx.x * 256 + threadIdx.x;    // 0..2047  (b*512 + d)
  int c  = blockIdx.y;                         // 0..127
  int b  = bd >> 9, d = bd & 511;
  const ushort* base = lin + ((size_t)b * 4096 + (size_t)c * 32) * 2048;
  float cth = 0.f, cbr = 0.f, cbi = 0.f;
  float cm = 1.f, cs = 1.f, sn = 0.f;
#pragma unroll 4
  for (int t = 0; t < 32; ++t) {
    const ushort* row = base + (size_t)t * 2048;
    float th = bf2f(row[d]);
    float z  = bf2f(row[512 + d]);
    float ir = bf2f(row[1024 + d]);
    float ii = bf2f(row[1536 + d]);
    float rt = __fdividef(1.f, 1.f + __expf(-z));
    cm *= fmaxf(rt, 1e-6f);
    cth += th;
    float s_, c_;
    __sincosf(cth, &s_, &c_);
    float im = __fdividef(1.f, fmaxf(cm, 1e-8f));
    float invr = im * c_, invi = -im * s_;
    float drive = 1.f - rt;
    float br_ = drive * ir, bi_ = drive * ii;
    cbr += invr * br_ - invi * bi_;
    cbi += invr * bi_ + invi * br_;
    cs = c_; sn = s_;
  }
  agg[(size_t)c * 2048 + bd] = make_float4(cm * cs, cm * sn, cbr, cbi);
}

__global__ __launch_bounds__(256) void scan_k2(const float4* __restrict__ agg,
                                               float2* __restrict__ h0) {
  int bd = blockIdx.x * 256 + threadIdx.x;    // 2048 threads
  float hr = 0.f, hi = 0.f;
  for (int cg = 0; cg < 16; ++cg) {
    float4 a[8];
#pragma unroll
    for (int u = 0; u < 8; ++u) a[u] = agg[(size_t)(cg * 8 + u) * 2048 + bd];
#pragma unroll
    for (int u = 0; u < 8; ++u) {
      h0[(size_t)(cg * 8 + u) * 2048 + bd] = make_float2(hr, hi);
      float tr = hr + a[u].z, ti = hi + a[u].w;
      hr = a[u].x * tr - a[u].y * ti;
      hi = a[u].x * ti + a[u].y * tr;
    }
  }
}

__global__ __launch_bounds__(256) void scan_k3(const ushort* __restrict__ lin,
                                               const float2* __restrict__ h0,
                                               ushort* __restrict__ outb) {
  int bd = blockIdx.x * 256 + threadIdx.x;
  int c  = blockIdx.y;
  int b  = bd >> 9, d = bd & 511;
  const ushort* base = lin + ((size_t)b * 4096 + (size_t)c * 32) * 2048;
  float2 h = h0[(size_t)c * 2048 + bd];
  float cth = 0.f, cbr = 0.f, cbi = 0.f, cm = 1.f;
#pragma unroll 4
  for (int t = 0; t < 32; ++t) {
    const ushort* row = base + (size_t)t * 2048;
    float th = bf2f(row[d]);
    float z  = bf2f(row[512 + d]);
    float ir = bf2f(row[1024 + d]);
    float ii = bf2f(row[1536 + d]);
    float rt = __fdividef(1.f, 1.f + __expf(-z));
    cm *= fmaxf(rt, 1e-6f);
    cth += th;
    float s_, c_;
    __sincosf(cth, &s_, &c_);
    float im = __fdividef(1.f, fmaxf(cm, 1e-8f));
    float invr = im * c_, invi = -im * s_;
    float drive = 1.f - rt;
    float br_ = drive * ir, bi_ = drive * ii;
    cbr += invr * br_ - invi * bi_;
    cbi += invr * bi_ + invi * br_;
    float ar = cm * c_, ai = cm * s_;
    float tr = h.x + cbr, ti = h.y + cbi;
    float orr = ar * tr - ai * ti;
    float oii = ar * ti + ai * tr;
    size_t rowo = ((size_t)b * 4096 + (size_t)c * 32 + t) * 1024;
    outb[rowo + d] = f2bf(orr);
    outb[rowo + 512 + d] = f2bf(oii);
  }
}

// ---------------------------------------------------------------------------
// LayerNorm, one WAVE per row (4 rows/block). yb already includes residual.
// ---------------------------------------------------------------------------
__global__ __launch_bounds__(256) void ln_k(const ushort* __restrict__ yb,
                                            const float* __restrict__ gamma,
                                            const float* __restrict__ beta,
                                            float* __restrict__ out) {
  const int lane = threadIdx.x & 63;
  const size_t row = (size_t)blockIdx.x * 4 + (threadIdx.x >> 6);
  const ushort* yr = yb + row * 1024;
  float v[4][4];
  float s = 0.f, s2 = 0.f;
#pragma unroll
  for (int q = 0; q < 4; ++q) {
    ushort4 uy = *(const ushort4*)(yr + q * 256 + lane * 4);
    v[q][0] = bf2f(uy.x);
    v[q][1] = bf2f(uy.y);
    v[q][2] = bf2f(uy.z);
    v[q][3] = bf2f(uy.w);
#pragma unroll
    for (int j = 0; j < 4; ++j) { s += v[q][j]; s2 += v[q][j] * v[q][j]; }
  }
#pragma unroll
  for (int off = 32; off > 0; off >>= 1) {
    s  += __shfl_xor(s, off);
    s2 += __shfl_xor(s2, off);
  }
  const float mu = s * (1.f / 1024.f);
  const float rstd = rsqrtf(s2 * (1.f / 1024.f) - mu * mu + 1e-5f);
#pragma unroll
  for (int q = 0; q < 4; ++q) {
    float4 gv = *(const float4*)(gamma + q * 256 + lane * 4);
    float4 bv = *(const float4*)(beta + q * 256 + lane * 4);
    float4 o;
    o.x = (v[q][0] - mu) * rstd * gv.x + bv.x;
    o.y = (v[q][1] - mu) * rstd * gv.y + bv.y;
    o.z = (v[q][2] - mu) * rstd * gv.z + bv.z;
    o.w = (v[q][3] - mu) * rstd * gv.w + bv.w;
    *(float4*)(out + row * 1024 + q * 256 + lane * 4) = o;
  }
}

// ---------------------------------------------------------------------------
extern "C" void kernel_launch(void* const* d_in, const int* in_sizes, int n_in,
                              void* d_out, int out_size, void* d_ws, size_t ws_size,
                              hipStream_t stream) {
  (void)in_sizes; (void)n_in; (void)out_size; (void)ws_size;
  const float* x  = (const float*)d_in[0];
  const float* Wt = (const float*)d_in[1];
  const float* bt = (const float*)d_in[2];
  const float* Wr = (const float*)d_in[3];
  const float* br = (const float*)d_in[4];
  const float* Wi = (const float*)d_in[5];
  const float* bi = (const float*)d_in[6];
  const float* Wo = (const float*)d_in[7];
  const float* bo = (const float*)d_in[8];
  const float* gamma = (const float*)d_in[9];
  const float* beta  = (const float*)d_in[10];

  char* ws = (char*)d_ws;
  ushort* wcat_t = (ushort*)(ws);                      //  4 MiB: [2048][1024] bf16
  ushort* wo_t   = (ushort*)(ws + ((size_t)4  << 20)); //  2 MiB: [1024][1024] bf16
  float*  bcat   = (float*) (ws + ((size_t)6  << 20)); //  8 KiB
  float4* agg    = (float4*)(ws + ((size_t)8  << 20)); //  4 MiB: [128][2048]
  float2* h0     = (float2*)(ws + ((size_t)12 << 20)); //  2 MiB: [128][2048]
  ushort* outb   = (ushort*)(ws + ((size_t)48 << 20)); // 32 MiB: scan out bf16
  ushort* linb   = (ushort*)(ws + ((size_t)80 << 20)); // 64 MiB: lin bf16
  ushort* yb     = (ushort*)(ws + ((size_t)80 << 20)); // 32 MiB: y bf16 (overlays dead linb)

  // weight prep (fused) + bias pack
  tconv_all<<<dim3(32, 32, 4), dim3(32, 8), 0, stream>>>(Wt, Wr, Wi, Wo, wcat_t, wo_t);
  pack_bias<<<8, 256, 0, stream>>>(bt, br, bi, bcat);

  // lin(bf16) = x(f32, converted in-kernel) @ [Wt|Wr|Wi] + [bt|br|bi]
  gemm256<true><<<512, 512, 0, stream>>>(x, wcat_t, linb, bcat, nullptr,
                                         16384, 2048, 1024, 8);

  // chunked complex scan
  scan_k1<<<dim3(8, 128), 256, 0, stream>>>(linb, agg);
  scan_k2<<<8, 256, 0, stream>>>(agg, h0);
  scan_k3<<<dim3(8, 128), 256, 0, stream>>>(linb, h0, outb);

  // yb(bf16) = out @ Wo + bo + x   (residual fused into epilogue; 256 blocks)
  gemm256<false><<<256, 512, 0, stream>>>(outb, wo_t, yb, bo, x,
                                          16384, 1024, 1024, 4);

  // layernorm(yb) -> d_out   (one wave per row; yb already has residual)
  ln_k<<<4096, 256, 0, stream>>>(yb, gamma, beta, (float*)d_out);
}